// Round 1
// baseline (764.064 us; speedup 1.0000x reference)
//
#include <hip/hip_runtime.h>

#define N_ACTC 80
#define M_CONC 85
#define NZC 84
#define MGC 169
#define RHO_C 10.0f
#define SIGMA_C 1e-6f
#define PEN_C 1000.0f
#define ITERS_C 200

// One sample per block. Register-resident A (col+row chunks) and K^{-1} (via
// in-register SPD sweep). LDS only for vectors/partials (~12KB).
__launch_bounds__(256, 3)
__global__ void qp_admm_kernel(const float* __restrict__ xraw,
                               const float* __restrict__ Ag,
                               const float* __restrict__ bg,
                               const float* __restrict__ lowg,
                               float* __restrict__ outp) {
  const int s = blockIdx.x;
  const int t = threadIdx.x;
  const float* A = Ag + (size_t)s * (M_CONC * N_ACTC);

  __shared__ __align__(16) float xr[80];
  __shared__ __align__(16) float rinv[96];
  __shared__ __align__(16) float slab[16 * 84];   // 16 rows, pitch 84 (cols 80..83 zero)
  __shared__ __align__(16) float u_lds[176];
  __shared__ __align__(16) float rhs_lds[84];
  __shared__ __align__(16) float z_lds[84];
  __shared__ __align__(16) float psumA[252];
  __shared__ __align__(16) float psumB[252];
  __shared__ __align__(16) float psumC[256];
  __shared__ __align__(16) float rkbuf[2][84];
  __shared__ __align__(16) float psq[256];

  const int iB = t % 84, pB = t / 84;   // K row iB, col run [pB*28, pB*28+28)  (t<252)
  const int iA = t % 80, pA = t / 80;   // A^T u: output col iA, row chunk pA*32 (t<240)
  const int rC = t % 85, pC = t / 85;   // A z: row rC, col run pC*28            (t<255)

  if (t < 80) xr[t] = xraw[s * 80 + t];
  if (t < 84) z_lds[t] = 0.f;
  if (t < 176) u_lds[t] = 0.f;
  if (t >= 85 && t < 96) rinv[t] = 0.f;

  float kacc[28];
#pragma unroll
  for (int jj = 0; jj < 28; ++jj) kacc[jj] = 0.f;
  float creg_c[28];
#pragma unroll
  for (int jj = 0; jj < 28; ++jj) creg_c[jj] = 0.f;

  // ---- slab loop: row norms, normalized A slabs, AtA accumulation, row cache
  for (int sl = 0; sl < 6; ++sl) {
    const int r0 = sl * 16;
    for (int e = t; e < 16 * 80; e += 256) {
      int rl = e / 80;
      int c = e - rl * 80;
      int r = r0 + rl;
      slab[rl * 84 + c] = (r < M_CONC) ? A[r * 80 + c] : 0.f;
    }
    if (t < 64) slab[(t >> 2) * 84 + 80 + (t & 3)] = 0.f;
    __syncthreads();
    {
      int rl = t >> 4, p = t & 15;
      float acc = 0.f;
#pragma unroll
      for (int c = 0; c < 5; ++c) {
        float v = slab[rl * 84 + p * 5 + c];
        acc += v * v;
      }
      psq[t] = acc;
    }
    __syncthreads();
    if (t < 16 && (r0 + t) < M_CONC) {
      float n2 = 0.f;
#pragma unroll
      for (int p = 0; p < 16; ++p) n2 += psq[t * 16 + p];
      float rn = fmaxf(sqrtf(n2), 1e-12f);
      rinv[r0 + t] = 1.0f / rn;
    }
    __syncthreads();
    for (int e = t; e < 16 * 80; e += 256) {
      int rl = e / 80;
      int c = e - rl * 80;
      slab[rl * 84 + c] *= rinv[r0 + rl];   // rows >=85 scale by 0 (stay 0)
    }
    __syncthreads();
    // AtA accumulation into registers (rank-16 update)
    if (t < 252 && iB < 80) {
      for (int rl = 0; rl < 16; ++rl) {
        float ai = slab[rl * 84 + iB];
#pragma unroll
        for (int jj = 0; jj < 28; ++jj)
          kacc[jj] += ai * slab[rl * 84 + pB * 28 + jj];
      }
    }
    // phase-C row cache (whole chunk comes from one slab -> static reg indices)
    if (t < 255 && rC >= r0 && rC < r0 + 16) {
      int rl = rC - r0;
#pragma unroll
      for (int jj = 0; jj < 28; ++jj) creg_c[jj] = slab[rl * 84 + pC * 28 + jj];
    }
    __syncthreads();   // NOTE: after last slab, slab[] holds normalized rows 80..84 at locals 0..4
  }

  // ---- phase-A column cache straight from global (coalesced: lanes consecutive in iA)
  float creg_a[32];
  if (t < 240) {
#pragma unroll
    for (int rr = 0; rr < 32; ++rr) {
      int r = pA * 32 + rr;
      creg_a[rr] = (r < M_CONC) ? A[r * 80 + iA] * rinv[r] : 0.f;
    }
  } else {
#pragma unroll
    for (int rr = 0; rr < 32; ++rr) creg_a[rr] = 0.f;
  }

  // ---- assemble K = RHO*G^T G + diag(pdiag + SIGMA) into registers
  float kreg[28];
  if (t < 252) {
#pragma unroll
    for (int jj = 0; jj < 28; ++jj) {
      int j = pB * 28 + jj;
      float v;
      if (iB < 80) {
        v = (j < 80)
              ? (RHO_C * kacc[jj] + ((j == iB) ? (RHO_C + 1.0f + SIGMA_C) : 0.f))
              : (-RHO_C * slab[(j - 80 + 1) * 84 + iB]);   // -RHO*A_soft[s][i], soft rows at locals 1..4
      } else {
        int ss = iB - 80;
        v = (j < 80)
              ? (-RHO_C * slab[(ss + 1) * 84 + j])
              : ((j - 80 == ss) ? (2.f * RHO_C + 2.f * PEN_C + SIGMA_C) : 0.f);
      }
      kreg[jj] = v;
    }
  } else {
#pragma unroll
    for (int jj = 0; jj < 28; ++jj) kreg[jj] = 0.f;
  }

  if (t < 252 && iB == 0) {
#pragma unroll
    for (int jj = 0; jj < 28; ++jj) rkbuf[0][pB * 28 + jj] = kreg[jj];
  }
  __syncthreads();

  // ---- SPD sweep (Gauss-Jordan) in registers; final kreg = -K^{-1}
  for (int k = 0; k < NZC; ++k) {
    const float* rk = rkbuf[k & 1];
    float dinv = 1.0f / rk[k];
    if (t < 252) {
      float t1 = rk[iB] * dinv;
      bool rowk = (iB == k);
      int jfix = k - pB * 28;
#pragma unroll
      for (int jj = 0; jj < 28; ++jj) {
        float rkj = rk[pB * 28 + jj];
        float gen = kreg[jj] - t1 * rkj;
        float val = rowk ? ((jj == jfix) ? -dinv : rkj * dinv)
                         : ((jj == jfix) ? t1 : gen);
        kreg[jj] = val;
      }
      if (k < NZC - 1 && iB == k + 1) {
#pragma unroll
        for (int jj = 0; jj < 28; ++jj) rkbuf[(k + 1) & 1][pB * 28 + jj] = kreg[jj];
      }
    }
    __syncthreads();
  }

  // ---- per-thread constraint state
  float yor_r = 0.f, h_r = 0.f;
  if (t < MGC) {
    if (t < 85) h_r = bg[s * 85 + t] * rinv[t];
    else if (t < 89) h_r = 0.f;
    else h_r = -lowg[s * 80 + (t - 89)];
  }
  __syncthreads();

  // ---- 200 ADMM iterations
  for (int it = 0; it < ITERS_C; ++it) {
    // phase A: partials of A^T u
    if (t < 240) {
      float acc = 0.f;
#pragma unroll
      for (int rr = 0; rr < 32; ++rr) acc += creg_a[rr] * u_lds[pA * 32 + rr];
      psumA[pA * 84 + iA] = acc;
    }
    __syncthreads();
    // combine-1: rhs = SIGMA z - q + G^T u
    if (t < 84) {
      float rhsv;
      if (t < 80)
        rhsv = psumA[t] + psumA[84 + t] + psumA[168 + t] + xr[t] + SIGMA_C * z_lds[t] - u_lds[89 + t];
      else {
        int ss = t - 80;
        rhsv = SIGMA_C * z_lds[t] - u_lds[81 + ss] - u_lds[85 + ss];
      }
      rhs_lds[t] = rhsv;
    }
    __syncthreads();
    // phase B: partials of (-K^{-1}) rhs
    if (t < 252) {
      float acc = 0.f;
#pragma unroll
      for (int jj = 0; jj < 28; ++jj) acc += kreg[jj] * rhs_lds[pB * 28 + jj];
      psumB[pB * 84 + iB] = acc;
    }
    __syncthreads();
    // combine-2: z = K^{-1} rhs  (negate the sweep result)
    if (t < 84) z_lds[t] = -(psumB[t] + psumB[84 + t] + psumB[168 + t]);
    __syncthreads();
    // phase C: partials of A x
    if (t < 255) {
      float acc = 0.f;
#pragma unroll
      for (int jj = 0; jj < 28; ++jj) acc += creg_c[jj] * z_lds[pC * 28 + jj];
      psumC[pC * 85 + rC] = acc;
    }
    __syncthreads();
    // update: Gz, v, w=min(v,h), u = RHO(2w - v), yor = v - w
    if (t < MGC) {
      float gz;
      if (t < 85) {
        gz = psumC[t] + psumC[85 + t] + psumC[170 + t];
        if (t >= 81) gz -= z_lds[80 + (t - 81)];
      } else if (t < 89) {
        gz = -z_lds[80 + (t - 85)];
      } else {
        gz = -z_lds[t - 89];
      }
      float v = gz + yor_r;
      float w = fminf(v, h_r);
      u_lds[t] = RHO_C * (2.f * w - v);
      yor_r = v - w;
    }
    __syncthreads();
  }

  if (t < 80) outp[s * 80 + t] = z_lds[t];
}

extern "C" void kernel_launch(void* const* d_in, const int* in_sizes, int n_in,
                              void* d_out, int out_size, void* d_ws, size_t ws_size,
                              hipStream_t stream) {
  const float* xraw = (const float*)d_in[0];
  const float* Ag   = (const float*)d_in[1];
  const float* bg   = (const float*)d_in[2];
  const float* lowg = (const float*)d_in[3];
  float* outp = (float*)d_out;
  const int B = in_sizes[0] / N_ACTC;
  qp_admm_kernel<<<B, 256, 0, stream>>>(xraw, Ag, bg, lowg, outp);
}